// Round 1
// baseline (3405.544 us; speedup 1.0000x reference)
//
#include <hip/hip_runtime.h>

#define C_NUM 1000
#define D_DIM 128
#define MOMENTUM 0.9f

// ws layout: [0, C*D) float sums ; [C*D, C*D + C) int counts
__global__ void zero_ws_kernel(float* __restrict__ ws, int n) {
    int i = blockIdx.x * blockDim.x + threadIdx.x;
    if (i < n) ws[i] = 0.0f;
}

__global__ void count_kernel(const int* __restrict__ labels, int n,
                             int* __restrict__ counts) {
    __shared__ int hist[C_NUM];
    for (int i = threadIdx.x; i < C_NUM; i += blockDim.x) hist[i] = 0;
    __syncthreads();
    int idx = blockIdx.x * blockDim.x + threadIdx.x;
    int stride = gridDim.x * blockDim.x;
    for (int i = idx; i < n; i += stride) {
        atomicAdd(&hist[labels[i]], 1);
    }
    __syncthreads();
    for (int i = threadIdx.x; i < C_NUM; i += blockDim.x) {
        int v = hist[i];
        if (v) atomicAdd(&counts[i], v);
    }
}

__global__ void scatter_kernel(const float4* __restrict__ feat4,
                               const int* __restrict__ labels,
                               float* __restrict__ sums, long total4) {
    long idx = (long)blockIdx.x * blockDim.x + threadIdx.x;
    long stride = (long)gridDim.x * blockDim.x;
    for (long i = idx; i < total4; i += stride) {
        float4 v = feat4[i];
        int row = (int)(i >> 5);   // 32 float4 per 128-wide row
        int q   = (int)(i & 31);
        int lab = labels[row];
        float* dst = sums + lab * D_DIM + q * 4;
        atomicAdd(dst + 0, v.x);
        atomicAdd(dst + 1, v.y);
        atomicAdd(dst + 2, v.z);
        atomicAdd(dst + 3, v.w);
    }
}

__global__ void finalize_kernel(const float* __restrict__ prototypes,
                                const float* __restrict__ sums,
                                const int* __restrict__ counts,
                                float* __restrict__ out) {
    __shared__ float red[D_DIM];
    int c = blockIdx.x;
    int d = threadIdx.x;
    float proto = prototypes[c * D_DIM + d];
    red[d] = proto;
    __syncthreads();
    for (int s = 64; s > 0; s >>= 1) {
        if (d < s) red[d] += red[d + s];
        __syncthreads();
    }
    float rowsum = red[0];
    int cnt = counts[c];
    float mean = sums[c * D_DIM + d] / (float)max(cnt, 1);
    float ema = MOMENTUM * proto + (1.0f - MOMENTUM) * mean;
    float res;
    if (cnt > 0) {
        res = (rowsum == 0.0f) ? mean : ema;
    } else {
        res = proto;
    }
    out[c * D_DIM + d] = res;
}

extern "C" void kernel_launch(void* const* d_in, const int* in_sizes, int n_in,
                              void* d_out, int out_size, void* d_ws, size_t ws_size,
                              hipStream_t stream) {
    const float* features   = (const float*)d_in[0];
    const int*   labels     = (const int*)d_in[1];
    const float* prototypes = (const float*)d_in[2];
    float* out = (float*)d_out;

    int n = in_sizes[1];                 // N = 2,000,000
    // C, D fixed by problem: 1000 x 128. out_size == C*D.

    float* sums  = (float*)d_ws;
    int*   counts = (int*)(sums + C_NUM * D_DIM);

    // zero sums + counts (C*D floats + C ints, both 4-byte words)
    int zero_n = C_NUM * D_DIM + C_NUM;
    zero_ws_kernel<<<(zero_n + 255) / 256, 256, 0, stream>>>((float*)d_ws, zero_n);

    count_kernel<<<512, 256, 0, stream>>>(labels, n, counts);

    long total4 = (long)n * (D_DIM / 4);
    scatter_kernel<<<2048, 256, 0, stream>>>((const float4*)features, labels, sums, total4);

    finalize_kernel<<<C_NUM, D_DIM, 0, stream>>>(prototypes, sums, counts, out);
}

// Round 2
// 621.466 us; speedup vs baseline: 5.4799x; 5.4799x over previous
//
#include <hip/hip_runtime.h>

#define C_NUM 1000
#define D_DIM 128
#define MOMENTUM 0.9f

// ===================== counting-sort path =====================
// ws layout (ints): counts[C], offsets[C], cursor[C], order[N]

__global__ void zero_counts_kernel(int* __restrict__ counts) {
    int i = blockIdx.x * blockDim.x + threadIdx.x;
    if (i < C_NUM) counts[i] = 0;
}

__global__ void hist_kernel(const int* __restrict__ labels, int n,
                            int* __restrict__ counts) {
    __shared__ int h[C_NUM];
    for (int i = threadIdx.x; i < C_NUM; i += blockDim.x) h[i] = 0;
    __syncthreads();
    int idx = blockIdx.x * blockDim.x + threadIdx.x;
    int stride = gridDim.x * blockDim.x;
    for (int i = idx; i < n; i += stride) atomicAdd(&h[labels[i]], 1);
    __syncthreads();
    for (int i = threadIdx.x; i < C_NUM; i += blockDim.x) {
        int v = h[i];
        if (v) atomicAdd(&counts[i], v);
    }
}

__global__ void scan_kernel(const int* __restrict__ counts,
                            int* __restrict__ offsets,
                            int* __restrict__ cursor) {
    __shared__ int s[1024];
    int t = threadIdx.x;
    int c = (t < C_NUM) ? counts[t] : 0;
    s[t] = c;
    __syncthreads();
    for (int d = 1; d < 1024; d <<= 1) {
        int v = (t >= d) ? s[t - d] : 0;
        __syncthreads();
        s[t] += v;
        __syncthreads();
    }
    if (t < C_NUM) {
        int off = s[t] - c;   // exclusive
        offsets[t] = off;
        cursor[t] = off;
    }
}

__global__ void build_order_kernel(const int* __restrict__ labels, int n,
                                   int* __restrict__ cursor,
                                   int* __restrict__ order) {
    int idx = blockIdx.x * blockDim.x + threadIdx.x;
    int stride = gridDim.x * blockDim.x;
    for (int i = idx; i < n; i += stride) {
        int lab = labels[i];
        int pos = atomicAdd(&cursor[lab], 1);
        order[pos] = i;
    }
}

__global__ __launch_bounds__(256) void class_reduce_kernel(
        const float4* __restrict__ feat4, const int* __restrict__ order,
        const int* __restrict__ counts, const int* __restrict__ offsets,
        const float* __restrict__ prototypes, float* __restrict__ out) {
    int c = blockIdx.x;
    int tid = threadIdx.x;
    int sub = tid >> 5;       // row-group 0..7
    int q = tid & 31;         // float4 index within row
    int off = offsets[c], cnt = counts[c];

    float4 acc = make_float4(0.f, 0.f, 0.f, 0.f);
    int j = off + sub;
    int end = off + cnt;
    // unrolled-by-2 to give the gather some ILP
    for (; j + 8 < end; j += 16) {
        int r0 = order[j];
        int r1 = order[j + 8];
        float4 v0 = feat4[(long)r0 * 32 + q];
        float4 v1 = feat4[(long)r1 * 32 + q];
        acc.x += v0.x + v1.x;
        acc.y += v0.y + v1.y;
        acc.z += v0.z + v1.z;
        acc.w += v0.w + v1.w;
    }
    if (j < end) {
        int r = order[j];
        float4 v = feat4[(long)r * 32 + q];
        acc.x += v.x; acc.y += v.y; acc.z += v.z; acc.w += v.w;
    }

    __shared__ float4 lds4[8 * 32];
    lds4[sub * 32 + q] = acc;
    __syncthreads();

    __shared__ float red[D_DIM];
    float mean = 0.f, proto = 0.f;
    if (tid < D_DIM) {
        const float* lds = (const float*)lds4;
        float s = 0.f;
        #pragma unroll
        for (int g = 0; g < 8; ++g) s += lds[g * D_DIM + tid];
        mean = s / (float)max(cnt, 1);
        proto = prototypes[c * D_DIM + tid];
        red[tid] = proto;
    }
    __syncthreads();
    for (int s2 = 64; s2 > 0; s2 >>= 1) {
        if (tid < s2) red[tid] += red[tid + s2];
        __syncthreads();
    }
    if (tid < D_DIM) {
        float rowsum = red[0];
        float ema = MOMENTUM * proto + (1.f - MOMENTUM) * mean;
        float res = (cnt > 0) ? ((rowsum == 0.f) ? mean : ema) : proto;
        out[c * D_DIM + tid] = res;
    }
}

// ===================== fallback (round-1 atomic path) =====================
__global__ void zero_ws_kernel(float* __restrict__ ws, int n) {
    int i = blockIdx.x * blockDim.x + threadIdx.x;
    if (i < n) ws[i] = 0.0f;
}

__global__ void scatter_kernel(const float4* __restrict__ feat4,
                               const int* __restrict__ labels,
                               float* __restrict__ sums, long total4) {
    long idx = (long)blockIdx.x * blockDim.x + threadIdx.x;
    long stride = (long)gridDim.x * blockDim.x;
    for (long i = idx; i < total4; i += stride) {
        float4 v = feat4[i];
        int row = (int)(i >> 5);
        int q = (int)(i & 31);
        int lab = labels[row];
        float* dst = sums + lab * D_DIM + q * 4;
        atomicAdd(dst + 0, v.x);
        atomicAdd(dst + 1, v.y);
        atomicAdd(dst + 2, v.z);
        atomicAdd(dst + 3, v.w);
    }
}

__global__ void finalize_kernel(const float* __restrict__ prototypes,
                                const float* __restrict__ sums,
                                const int* __restrict__ counts,
                                float* __restrict__ out) {
    __shared__ float red[D_DIM];
    int c = blockIdx.x;
    int d = threadIdx.x;
    float proto = prototypes[c * D_DIM + d];
    red[d] = proto;
    __syncthreads();
    for (int s = 64; s > 0; s >>= 1) {
        if (d < s) red[d] += red[d + s];
        __syncthreads();
    }
    float rowsum = red[0];
    int cnt = counts[c];
    float mean = sums[c * D_DIM + d] / (float)max(cnt, 1);
    float ema = MOMENTUM * proto + (1.0f - MOMENTUM) * mean;
    float res = (cnt > 0) ? ((rowsum == 0.0f) ? mean : ema) : proto;
    out[c * D_DIM + d] = res;
}

// =========================================================================
extern "C" void kernel_launch(void* const* d_in, const int* in_sizes, int n_in,
                              void* d_out, int out_size, void* d_ws, size_t ws_size,
                              hipStream_t stream) {
    const float* features   = (const float*)d_in[0];
    const int*   labels     = (const int*)d_in[1];
    const float* prototypes = (const float*)d_in[2];
    float* out = (float*)d_out;
    int n = in_sizes[1];

    size_t need = (size_t)(3 * C_NUM + n) * sizeof(int);
    if (ws_size >= need) {
        int* counts  = (int*)d_ws;
        int* offsets = counts + C_NUM;
        int* cursor  = offsets + C_NUM;
        int* order   = cursor + C_NUM;

        zero_counts_kernel<<<(C_NUM + 255) / 256, 256, 0, stream>>>(counts);
        hist_kernel<<<512, 256, 0, stream>>>(labels, n, counts);
        scan_kernel<<<1, 1024, 0, stream>>>(counts, offsets, cursor);
        build_order_kernel<<<1024, 256, 0, stream>>>(labels, n, cursor, order);
        class_reduce_kernel<<<C_NUM, 256, 0, stream>>>(
            (const float4*)features, order, counts, offsets, prototypes, out);
    } else {
        float* sums = (float*)d_ws;
        int* counts = (int*)(sums + C_NUM * D_DIM);
        int zero_n = C_NUM * D_DIM + C_NUM;
        zero_ws_kernel<<<(zero_n + 255) / 256, 256, 0, stream>>>((float*)d_ws, zero_n);
        hist_kernel<<<512, 256, 0, stream>>>(labels, n, counts);
        long total4 = (long)n * (D_DIM / 4);
        scatter_kernel<<<2048, 256, 0, stream>>>((const float4*)features, labels, sums, total4);
        finalize_kernel<<<C_NUM, D_DIM, 0, stream>>>(prototypes, sums, counts, out);
    }
}